// Round 11
// baseline (158.512 us; speedup 1.0000x reference)
//
#include <hip/hip_runtime.h>
#include <hip/hip_bf16.h>
#include <stdint.h>

#define DI __device__ __forceinline__

typedef float f32x4 __attribute__((ext_vector_type(4)));
typedef short bf16x8 __attribute__((ext_vector_type(8)));

constexpr int BB = 8192, TT = 128, DD = 16, HH = 32;
constexpr float kEPS = 1e-5f;
constexpr float kLOG2E = 1.44269504088896340736f;

// ---------------- helpers ----------------
DI float rcpf_(float x) { return __builtin_amdgcn_rcpf(x); }
DI float exp2f_(float x) { return __builtin_amdgcn_exp2f(x); }
DI float sigm(float x) { return rcpf_(1.0f + exp2f_(-kLOG2E * x)); }

DI uint32_t cvtpk(float lo, float hi) {
  uint32_t r;
  asm("v_cvt_pk_bf16_f32 %0, %1, %2" : "=v"(r) : "v"(lo), "v"(hi));
  return r;
}

DI f32x4 mfma_(bf16x8 a, bf16x8 b, f32x4 c) {
  return __builtin_amdgcn_mfma_f32_16x16x32_bf16(a, b, c, 0, 0, 0);
}

union U4 { uint4 q; bf16x8 v; uint32_t u[4]; };

// ---------------- weight prep (per net) ----------------
// W tiles are the MFMA *A* operand, state is *B*.
// k-slot permutation pi (both operands):  pi(8g+j) = j<4 ? 4g+j : 16+4g+(j-4)
// With pi, the MFMA C-layout (lane c+16g holds dims {4g+r, 16+4g+r}) IS the
// B-frag layout -> recurrent state repack = 4 in-lane cvt_pk, NO cross-lane.
__global__ void prep_net(const float* Wih0, const float* Whh0,
                         const float* bih0, const float* bhh0,
                         const float* Wih1, const float* Whh1,
                         const float* bih1, const float* bhh1,
                         const float* embW, const float* embB,
                         const float* bng, const float* bnb,
                         const float* bnm, const float* bnv,
                         const float* outW, const float* outB,
                         int outDim, uint8_t* wsbase) {
  int tid = threadIdx.x;
  uint16_t* W = (uint16_t*)wsbase;
  float* bias = (float*)(wsbase + 27648);
  auto cvt = [](float f) -> uint16_t {
    union { float f; uint32_t u; } v; v.f = f;
    uint32_t u = v.u;
    return (uint16_t)((u + 0x7FFF + ((u >> 16) & 1)) >> 16);  // RNE
  };
  for (int idx = tid; idx < 27 * 64; idx += 256) {
    int tile = idx >> 6, l = idx & 63, cc = l & 15, gg = l >> 4;
    uint16_t* dst = W + (size_t)idx * 8;
    if (tile < 24) {
      const float* mats[4] = {Wih0, Whh0, Wih1, Whh1};
      const float* src = mats[tile / 6];
      int sub = tile % 6;                   // r0 r1 z0 z1 n0 n1
      int row = sub * 16 + cc;              // rows: r 0-31, z 32-63, n 64-95
      float sc = (sub < 4) ? -kLOG2E : 2.0f * kLOG2E;
#pragma unroll
      for (int j = 0; j < 8; ++j) {
        int k = (j < 4) ? 4 * gg + j : 16 + 4 * gg + (j - 4);  // pi
        dst[j] = cvt(src[row * 32 + k] * sc);
      }
    } else if (tile < 26) {
      int row = (tile - 24) * 16 + cc;
      float a = bng[row] * rsqrtf(bnv[row] + kEPS);
#pragma unroll
      for (int j = 0; j < 8; ++j) {
        int k = (j < 4) ? 4 * gg + j : 16 + 4 * gg + (j - 4);  // pi
        dst[j] = cvt(embW[row * 32 + k] * a);
      }
    } else {
      int rrow = (cc < outDim) ? cc : 0;
      float sc = (cc < outDim) ? 1.0f : 0.0f;
#pragma unroll
      for (int j = 0; j < 8; ++j) {
        int k = (j < 4) ? 4 * gg + j : 16 + 4 * gg + (j - 4);  // pi
        dst[j] = cvt(outW[rrow * 32 + k] * sc);
      }
    }
  }
  for (int idx = tid; idx < 304; idx += 256) {
    int tile = idx >> 4, n = idx & 15;
    float v;
    if (tile < 8) {
      if (tile < 4)      v = (bih0[tile * 16 + n] + bhh0[tile * 16 + n]) * (-kLOG2E);
      else if (tile < 6) v = bih0[64 + (tile - 4) * 16 + n] * (2.0f * kLOG2E);
      else               v = bhh0[64 + (tile - 6) * 16 + n] * (2.0f * kLOG2E);
    } else if (tile < 16) {
      int tt = tile - 8;
      if (tt < 4)        v = (bih1[tt * 16 + n] + bhh1[tt * 16 + n]) * (-kLOG2E);
      else if (tt < 6)   v = bih1[64 + (tt - 4) * 16 + n] * (2.0f * kLOG2E);
      else               v = bhh1[64 + (tt - 6) * 16 + n] * (2.0f * kLOG2E);
    } else if (tile < 18) {
      int nn = (tile - 16) * 16 + n;
      float a = bng[nn] * rsqrtf(bnv[nn] + kEPS);
      v = a * (embB[nn] - bnm[nn]) + bnb[nn];
    } else {
      v = (n < outDim) ? outB[n] : 0.0f;
    }
    bias[idx] = v;
  }
}

// ---- fused RNN + heads: 3-stage ASYNC pipeline (R7 skeleton, R9 math) ----
// Block = 192 threads = 3 waves, one batch group (16 rows) of one net.
// Wave A: layer-0 recurrence -> ring0.   Wave B: layer-1 -> ring1.
// Wave C: head + stores. Flags (steps completed): 0=A-prod, 1=B-cons,
// 2=B-prod, 3=C-cons. Sync batched 2 steps per update; rings depth 8.
// Zero cross-lane permutes (pi layout).
__global__ __launch_bounds__(192, 3) void rnn_fused(
    const float* __restrict__ S, const float* __restrict__ gS,
    const float* __restrict__ hp0, const float* __restrict__ hd0,
    const uint8_t* __restrict__ ws, float* __restrict__ out) {
  const int tid = threadIdx.x, lane = tid & 63, wid = tid >> 6;
  const int net = blockIdx.x & 1;                 // 0 = price, 1 = delta
  const int b0 = (blockIdx.x >> 1) * 16;
  const int c = lane & 15, g = lane >> 4;

  const uint16_t* W = (const uint16_t*)(ws + net * 32768);
  const float* bias = (const float*)(ws + net * 32768 + 27648);
  const float* hsrc = net ? hd0 : hp0;

  __shared__ uint4 ring0[8][64];
  __shared__ uint4 ring1[8][64];
  __shared__ volatile int flags[4];
  if (tid < 4) flags[tid] = 0;
  __syncthreads();                                // only block-wide barrier

  auto waitGE = [&](int idx, int target) {
    if (flags[idx] >= target) return;
    do { __builtin_amdgcn_s_sleep(1); } while (flags[idx] < target);
  };

  // acc/C-layout h[8] -> B-frag: pure in-lane pack (pi layout)
  auto packB = [&](const float (&v)[8]) -> bf16x8 {
    U4 t;
    t.u[0] = cvtpk(v[0], v[1]); t.u[1] = cvtpk(v[2], v[3]);
    t.u[2] = cvtpk(v[4], v[5]); t.u[3] = cvtpk(v[6], v[7]);
    return t.v;
  };

  // GRU step, fused-rcp algebra: h' = [(h-Ez)+En*(h+Ez)]*rcp[(1+En)(1+Ez)]
  auto gruStep = [&](const bf16x8 (&Wi)[6], const bf16x8 (&Wh)[6],
                     const f32x4 (&Bb)[8], bf16x8 xf, bf16x8 hf,
                     float (&hC)[8]) {
    f32x4 r0 = mfma_(Wi[0], xf, Bb[0]); r0 = mfma_(Wh[0], hf, r0);
    f32x4 r1 = mfma_(Wi[1], xf, Bb[1]); r1 = mfma_(Wh[1], hf, r1);
    f32x4 z0 = mfma_(Wi[2], xf, Bb[2]); z0 = mfma_(Wh[2], hf, z0);
    f32x4 z1 = mfma_(Wi[3], xf, Bb[3]); z1 = mfma_(Wh[3], hf, z1);
    f32x4 ni0 = mfma_(Wi[4], xf, Bb[4]);
    f32x4 ni1 = mfma_(Wi[5], xf, Bb[5]);
    f32x4 nh0 = mfma_(Wh[4], hf, Bb[6]);
    f32x4 nh1 = mfma_(Wh[5], hf, Bb[7]);
#pragma unroll
    for (int r = 0; r < 4; ++r) {
      float rg0 = rcpf_(1.0f + exp2f_(r0[r]));
      float rg1 = rcpf_(1.0f + exp2f_(r1[r]));
      float w0 = ni0[r] + rg0 * nh0[r];
      float w1 = ni1[r] + rg1 * nh1[r];
      float En0 = exp2f_(w0), En1 = exp2f_(w1);
      float Ez0 = exp2f_(z0[r]), Ez1 = exp2f_(z1[r]);
      float hv0 = hC[r], hv1 = hC[4 + r];
      float num0 = (hv0 - Ez0) + En0 * (hv0 + Ez0);
      float num1 = (hv1 - Ez1) + En1 * (hv1 + Ez1);
      float den0 = (1.0f + En0) * (1.0f + Ez0);
      float den1 = (1.0f + En1) * (1.0f + Ez1);
      hC[r]     = num0 * rcpf_(den0);
      hC[4 + r] = num1 * rcpf_(den1);
    }
  };

  // initial state load in pi B-frag layout + acc layout (same dims per lane)
  auto loadState = [&](const float* row, float (&hC)[8]) -> bf16x8 {
    f32x4 a = *(const f32x4*)(row + 4 * g);        // dims 4g..4g+3
    f32x4 b = *(const f32x4*)(row + 16 + 4 * g);   // dims 16+4g..16+4g+3
#pragma unroll
    for (int r = 0; r < 4; ++r) { hC[r] = a[r]; hC[4 + r] = b[r]; }
    U4 t;
    t.u[0] = cvtpk(a[0], a[1]); t.u[1] = cvtpk(a[2], a[3]);
    t.u[2] = cvtpk(b[0], b[1]); t.u[3] = cvtpk(b[2], b[3]);
    return t.v;
  };

  if (wid == 0) {
    // ================= wave A: layer-0 recurrence (producer) =============
    bf16x8 Wi[6], Wh[6];
#pragma unroll
    for (int t = 0; t < 6; ++t) {
      Wi[t] = *(const bf16x8*)(W + ((0 + t) * 64 + lane) * 8);
      Wh[t] = *(const bf16x8*)(W + ((6 + t) * 64 + lane) * 8);
    }
    f32x4 Bb[8];
#pragma unroll
    for (int t = 0; t < 8; ++t)
      Bb[t] = *(const f32x4*)(bias + t * 16 + 4 * g);

    float h0C[8];
    bf16x8 h0B = loadState(hsrc + (size_t)(b0 + c) * HH, h0C);

    // x B-frag (pi layout): slots j<4 = S[4g+j], j>=4 = gS broadcast.
    auto mkX = [&](f32x4 sv, float gsv) -> bf16x8 {
      uint32_t pkg = cvtpk(gsv, gsv);
      U4 t;
      t.u[0] = cvtpk(sv[0], sv[1]);
      t.u[1] = cvtpk(sv[2], sv[3]);
      t.u[2] = pkg;
      t.u[3] = pkg;
      return t.v;
    };

    const float* Sbase  = S  + (size_t)(b0 + c) * TT * DD + 4 * g;
    const float* gSbase = gS + (size_t)(b0 + c) * TT;
    auto loadX = [&](int t, f32x4& a, float& gv) {
      a = *(const f32x4*)(Sbase + (size_t)t * DD); gv = gSbase[t];
    };

    f32x4 ca0, ca1, na0, na1;
    float cg0, cg1, ng0, ng1;
    loadX(TT - 1, ca0, cg0);
    loadX(TT - 2, ca1, cg1);

#pragma unroll 1
    for (int ip = 0; ip < TT / 2; ++ip) {
      int tn0 = TT - 3 - 2 * ip; if (tn0 < 0) tn0 = 0;
      int tn1 = TT - 4 - 2 * ip; if (tn1 < 0) tn1 = 0;
      loadX(tn0, na0, ng0);                      // prefetch next pair
      loadX(tn1, na1, ng1);

      bf16x8 x0 = mkX(ca0, cg0);
      gruStep(Wi, Wh, Bb, x0, h0B, h0C);
      h0B = packB(h0C);
      U4 f0v; f0v.v = h0B;
      bf16x8 x1 = mkX(ca1, cg1);
      gruStep(Wi, Wh, Bb, x1, h0B, h0C);
      h0B = packB(h0C);
      U4 f1v; f1v.v = h0B;

      if (ip >= 4) waitGE(1, 2 * ip - 6);        // ring0 backpressure
      asm volatile("" ::: "memory");
      ring0[(2 * ip) & 7][lane]     = f0v.q;
      ring0[(2 * ip + 1) & 7][lane] = f1v.q;
      asm volatile("s_waitcnt lgkmcnt(0)" ::: "memory");
      if (lane == 0) flags[0] = 2 * ip + 2;

      ca0 = na0; cg0 = ng0;
      ca1 = na1; cg1 = ng1;
    }
  } else if (wid == 1) {
    // ================= wave B: layer-1 recurrence ========================
    bf16x8 Wi[6], Wh[6];
#pragma unroll
    for (int t = 0; t < 6; ++t) {
      Wi[t] = *(const bf16x8*)(W + ((12 + t) * 64 + lane) * 8);
      Wh[t] = *(const bf16x8*)(W + ((18 + t) * 64 + lane) * 8);
    }
    f32x4 Bb[8];
#pragma unroll
    for (int t = 0; t < 8; ++t)
      Bb[t] = *(const f32x4*)(bias + (8 + t) * 16 + 4 * g);

    float h1C[8];
    bf16x8 h1B = loadState(hsrc + ((size_t)BB + b0 + c) * HH, h1C);

#pragma unroll 1
    for (int ip = 0; ip < TT / 2; ++ip) {
      waitGE(0, 2 * ip + 2);                     // wait for h0 pair
      asm volatile("" ::: "memory");
      U4 u0, u1;
      u0.q = ring0[(2 * ip) & 7][lane];
      u1.q = ring0[(2 * ip + 1) & 7][lane];
      asm volatile("s_waitcnt lgkmcnt(0)" ::: "memory");
      if (lane == 0) flags[1] = 2 * ip + 2;      // ring0 slots free

      gruStep(Wi, Wh, Bb, u0.v, h1B, h1C);
      h1B = packB(h1C);
      U4 f0v; f0v.v = h1B;
      gruStep(Wi, Wh, Bb, u1.v, h1B, h1C);
      h1B = packB(h1C);
      U4 f1v; f1v.v = h1B;

      if (ip >= 4) waitGE(3, 2 * ip - 6);        // ring1 backpressure
      asm volatile("" ::: "memory");
      ring1[(2 * ip) & 7][lane]     = f0v.q;
      ring1[(2 * ip + 1) & 7][lane] = f1v.q;
      asm volatile("s_waitcnt lgkmcnt(0)" ::: "memory");
      if (lane == 0) flags[2] = 2 * ip + 2;
    }
  } else {
    // ================= wave C: heads + stores ============================
    bf16x8 We0 = *(const bf16x8*)(W + (24 * 64 + lane) * 8);
    bf16x8 We1 = *(const bf16x8*)(W + (25 * 64 + lane) * 8);
    bf16x8 Wo  = *(const bf16x8*)(W + (26 * 64 + lane) * 8);
    const f32x4 Be0 = *(const f32x4*)(bias + 16 * 16 + 4 * g);
    const f32x4 Be1 = *(const f32x4*)(bias + 17 * 16 + 4 * g);
    const f32x4 Bo  = *(const f32x4*)(bias + 18 * 16 + 4 * g);

    auto head = [&](bf16x8 h1f, int th) {
      f32x4 e0 = mfma_(We0, h1f, Be0);
      f32x4 e1 = mfma_(We1, h1f, Be1);
      float es[8];
#pragma unroll
      for (int r = 0; r < 4; ++r) {
        float a = e0[r], b = e1[r];
        es[r]     = a * sigm(a);
        es[4 + r] = b * sigm(b);
      }
      bf16x8 ef = packB(es);                     // in-lane, pi layout
      f32x4 o = mfma_(Wo, ef, Bo);
      if (net == 0) {
        if (lane < 16) out[(size_t)(b0 + c) * TT + th] = o[0];
      } else {
        f32x4 so;
#pragma unroll
        for (int r = 0; r < 4; ++r) so[r] = sigm(o[r]);
        *(f32x4*)(out + (size_t)BB * TT +
                  ((size_t)(b0 + c) * TT + th) * DD + 4 * g) = so;
      }
    };

#pragma unroll 1
    for (int ip = 0; ip < TT / 2; ++ip) {
      waitGE(2, 2 * ip + 2);                     // wait for h1 pair
      asm volatile("" ::: "memory");
      U4 u0, u1;
      u0.q = ring1[(2 * ip) & 7][lane];
      u1.q = ring1[(2 * ip + 1) & 7][lane];
      asm volatile("s_waitcnt lgkmcnt(0)" ::: "memory");
      if (lane == 0) flags[3] = 2 * ip + 2;      // ring1 slots free

      head(u0.v, TT - 1 - 2 * ip);               // independent pair -> ILP
      head(u1.v, TT - 2 - 2 * ip);
    }
  }
}

// ---------------- launch ----------------
extern "C" void kernel_launch(void* const* d_in, const int* in_sizes, int n_in,
                              void* d_out, int out_size, void* d_ws,
                              size_t ws_size, hipStream_t stream) {
  const float* S   = (const float*)d_in[0];
  const float* gS  = (const float*)d_in[1];
  const float* hp0 = (const float*)d_in[5];
  const float* hd0 = (const float*)d_in[6];
  uint8_t* ws = (uint8_t*)d_ws;

  prep_net<<<1, 256, 0, stream>>>(
      (const float*)d_in[7],  (const float*)d_in[8],  (const float*)d_in[9],
      (const float*)d_in[10], (const float*)d_in[11], (const float*)d_in[12],
      (const float*)d_in[13], (const float*)d_in[14], (const float*)d_in[15],
      (const float*)d_in[16], (const float*)d_in[17], (const float*)d_in[18],
      (const float*)d_in[19], (const float*)d_in[20], (const float*)d_in[21],
      (const float*)d_in[22], 1, ws);
  prep_net<<<1, 256, 0, stream>>>(
      (const float*)d_in[23], (const float*)d_in[24], (const float*)d_in[25],
      (const float*)d_in[26], (const float*)d_in[27], (const float*)d_in[28],
      (const float*)d_in[29], (const float*)d_in[30], (const float*)d_in[31],
      (const float*)d_in[32], (const float*)d_in[33], (const float*)d_in[34],
      (const float*)d_in[35], (const float*)d_in[36], (const float*)d_in[37],
      (const float*)d_in[38], 16, ws + 32768);

  rnn_fused<<<dim3((BB / 16) * 2), dim3(192), 0, stream>>>(S, gS, hp0, hd0,
                                                           ws, (float*)d_out);
}